// Round 3
// baseline (194.752 us; speedup 1.0000x reference)
//
#include <hip/hip_runtime.h>

#define NN 20000
#define NE 320000
#define NG 256
#define CAPD 48           // dst-side bucket capacity (yq rows); P(deg>48) ~ 1e-12
#define ZS 148            // Ztab row stride (147 used)
#define YQS 32            // yq row stride in floats = 128 B = exactly one cache line
#define PROWS 32          // partial spread rows
#define BINS 10           // src-range bins (bin = s >> 11); Ztab slice 1.2 MB < 4 MB L2/XCD
#define BINSH 11
#define BCAP 36864        // records per bin (expected 32768, sigma ~171 -> 24 sigma)
#define RECF 12           // record floats: [ea(7) | pk(int: p | bg<<21) | s(int) | px py pz]

// yq row (32 floats): [y(21) | sh(8) | 0,0,0]  -- one aligned 128 B line per edge
//   sh = {s3*px, s3*py, s3*pz, s15*px*py, s15*py*pz, 1.118*(3pz^2-r2), s15*px*pz, 1.936*(px^2-py^2)}
// y col = g*7+v; scale factors folded into WV.
// Binned record stream makes Ztab/rtab re-reads L2-local; records read sequentially.

// ---------------- K0: WV[u][147] = folded W*V weights (tiny) ----------------

__global__ __launch_bounds__(256) void k_wv(
    const float* __restrict__ W1, const float* __restrict__ W2,
    const float* __restrict__ W3, const float* __restrict__ V1,
    const float* __restrict__ V2, const float* __restrict__ V3,
    float* __restrict__ WV)
{
    const int idx = blockIdx.x * 256 + threadIdx.x;   // 23*147 = 3381
    if (idx < 23 * 147) {
        const int u = idx / 147, c = idx - u * 147;
        const int vp = c / 21, col = c - vp * 21;
        const int g = col / 7, v = col - g * 7;
        float sum = 0.f;
        if (g == 0) {
            for (int w = 0; w < 64; ++w)
                sum += W1[(u*7 + vp)*64 + w] * V1[w*7 + v];
            sum *= 0.07881104f * 0.04724556f;   // a1 * 1/sqrt(64*7)
        } else if (g == 1) {
            for (int w = 0; w < 24; ++w)
                sum += W2[(u*7 + vp)*24 + w] * V2[w*7 + v];
            sum *= 0.07881104f * 0.04454354f;   // a1 * 1/sqrt(24*7*3)
        } else {
            for (int w = 0; w < 16; ++w)
                sum += W3[(u*7 + vp)*16 + w] * V3[w*7 + v];
            sum *= 0.07881104f * 0.04225771f;   // a1 * 1/sqrt(16*7*5)
        }
        WV[idx] = sum;                           // [u][147], c = v'*21 + col
    }
}

// ---------------- K1: counting-scatter edges into src-range bins ----------------
// Dense per-bin runs via LDS histogram + one global base claim per bin per block.

__global__ __launch_bounds__(256) void k_binsort(
    const float* __restrict__ pos,
    const float* __restrict__ eag,
    const int* __restrict__ esrc,
    const int* __restrict__ edst,
    const int* __restrict__ batch,
    int* __restrict__ deg_d,
    int* __restrict__ bincnt,
    float* __restrict__ binbuf)
{
    __shared__ int hist[BINS], base[BINS], off[BINS];
    const int t = threadIdx.x;
    const int e = blockIdx.x * 256 + t;       // 1250*256 == NE
    if (t < BINS) { hist[t] = 0; off[t] = 0; }
    __syncthreads();

    const int s = esrc[e], d = edst[e];
    const int bin = s >> BINSH;
    const int sd = atomicAdd(&deg_d[d], 1);
    const bool ok = (sd < CAPD);              // overflow edge dropped (P ~ 0)
    if (ok) atomicAdd(&hist[bin], 1);

    const int bg = batch[d];
    float ea[7];
#pragma unroll
    for (int v = 0; v < 7; ++v) ea[v] = eag[(size_t)e * 7 + v];
    const float px = pos[3*s+0] - pos[3*d+0];
    const float py = pos[3*s+1] - pos[3*d+1];
    const float pz = pos[3*s+2] - pos[3*d+2];

    __syncthreads();
    if (t < BINS) base[t] = atomicAdd(&bincnt[t], hist[t]);
    __syncthreads();

    if (ok) {
        const int slot = base[bin] + atomicAdd(&off[bin], 1);
        if (slot < BCAP) {                    // ~impossible overflow guard
            const int p  = d * CAPD + sd;     // p < 960000 < 2^20
            const int pk = p | (bg << 21);
            float* r = binbuf + ((size_t)bin * BCAP + slot) * RECF;
#pragma unroll
            for (int v = 0; v < 7; ++v) r[v] = ea[v];
            ((int*)r)[7] = pk;
            ((int*)r)[8] = s;
            r[9] = px; r[10] = py; r[11] = pz;
        }
    }
}

// ---------------- K2: Ztab[n][c] = sum_u x[n][u] * WV[u][c]  (8 nodes/block) ----------------

__global__ __launch_bounds__(256) void k_ztab(const float* __restrict__ x,
                                              const float* __restrict__ WV,
                                              float* __restrict__ Ztab)
{
    __shared__ float xa[8][23];
    const int b = blockIdx.x, t = threadIdx.x;   // grid 2500 exact
    const int base = b * 8;
    if (t < 184) {
        const int nl = t / 23, u = t - nl * 23;
        xa[nl][u] = x[(size_t)(base + nl) * 23 + u];
    }
    __syncthreads();
    if (t < 147) {
        float acc[8];
#pragma unroll
        for (int n = 0; n < 8; ++n) acc[n] = 0.f;
        for (int u = 0; u < 23; ++u) {
            const float wv = WV[u * 147 + t];     // coalesced
#pragma unroll
            for (int n = 0; n < 8; ++n) acc[n] += xa[n][u] * wv;
        }
#pragma unroll
        for (int n = 0; n < 8; ++n)
            Ztab[(size_t)(base + n) * ZS + t] = acc[n];
    }
}

// ---------------- K3: record-parallel; 32 lanes/record -> one 128 B yq line ----------
// Records processed bin-by-bin => Ztab slice (1.2 MB) is L2-resident.

__global__ __launch_bounds__(256) void k_yedge(const float* __restrict__ Ztab,
                                               const float* __restrict__ binbuf,
                                               const int* __restrict__ bincnt,
                                               float* __restrict__ yq)
{
    const int t = threadIdx.x;
    const int bid = blockIdx.x;                 // grid = BINS * (BCAP/8)
    const int bin = bid / (BCAP / 8);
    const int r0  = (bid % (BCAP / 8)) * 8;
    const int cnt = min(bincnt[bin], BCAP);
    if (r0 >= cnt) return;                      // uniform across block

    const int ri = r0 + (t >> 5);
    if (ri >= cnt) return;                      // per-half-wave exec mask
    const float* rec = binbuf + ((size_t)bin * BCAP + ri) * RECF;
    const int col = t & 31;
    const int p = ((const int*)rec)[7] & 0x1FFFFF;

    float val;
    if (col < 21) {
        const int s = ((const int*)rec)[8];
        const float* z = Ztab + (size_t)s * ZS;
        float y = 0.f;
#pragma unroll
        for (int v = 0; v < 7; ++v)
            y += rec[v] * z[21 * v + col];
        val = y;
    } else if (col < 29) {
        const float px = rec[9], py = rec[10], pz = rec[11];
        const float r2 = px*px + py*py + pz*pz;
        const float h0 = 1.7320508f*px, h1 = 1.7320508f*py, h2 = 1.7320508f*pz;
        const float h3 = 3.8729833f*px*py, h4 = 3.8729833f*py*pz;
        const float h5 = 1.1180340f*(3.f*pz*pz - r2);
        const float h6 = 3.8729833f*px*pz;
        const float h7 = 1.9364917f*(px*px - py*py);
        const int c = col - 21;
        val = (c == 0) ? h0 : (c == 1) ? h1 : (c == 2) ? h2 : (c == 3) ? h3
            : (c == 4) ? h4 : (c == 5) ? h5 : (c == 6) ? h6 : h7;
    } else {
        val = 0.f;
    }
    yq[(size_t)p * YQS + col] = val;            // one aligned 128 B line per record
}

// ---------------- K4: wave per dst node; single-stream reduction of its bucket ----------------
// rtab row (64 fp32): [r0[v](7) | r1[m,v] m-major (21) | r2[m,v] m-major (35) | pad]

__global__ __launch_bounds__(256) void k_racc(const float* __restrict__ yq,
                                              const int* __restrict__ deg_d,
                                              float* __restrict__ rtab)
{
    const int t = threadIdx.x, lane = t & 63;
    const int node = __builtin_amdgcn_readfirstlane(blockIdx.x * 4 + (t >> 6));
    const int dg = min(deg_d[node], CAPD);

    int col, sidx; bool unit;
    if (lane < 7)       { col = lane;              sidx = 0;          unit = true;  }
    else if (lane < 28) { const int i = lane - 7;  col = 7  + i % 7;  sidx = i / 7;     unit = false; }
    else if (lane < 63) { const int i = lane - 28; col = 14 + i % 7;  sidx = 3 + i / 7; unit = false; }
    else                { col = 0;                 sidx = 0;          unit = true;  }

    const float* yb = yq + (size_t)node * (CAPD * YQS);

    float acc = 0.f;
    int r = 0;
    for (; r + 4 <= dg; r += 4) {
        float yv[4], sv[4];
#pragma unroll
        for (int k = 0; k < 4; ++k) yv[k] = yb[(r + k) * YQS + col];
#pragma unroll
        for (int k = 0; k < 4; ++k) sv[k] = yb[(r + k) * YQS + 21 + sidx];
#pragma unroll
        for (int k = 0; k < 4; ++k) acc += (unit ? 1.f : sv[k]) * yv[k];
    }
    for (; r < dg; ++r) {
        const float yv = yb[r * YQS + col];
        const float sv = yb[r * YQS + 21 + sidx];
        acc += (unit ? 1.f : sv) * yv;
    }

    rtab[(size_t)node * 64 + lane] = (lane < 63) ? acc : 0.f;
}

// ---------------- K5: record-parallel; 8 lanes/record; rtab slice L2-resident ----

__global__ __launch_bounds__(256) void k_gfinal(const float* __restrict__ rtab,
                                                const float* __restrict__ binbuf,
                                                const int* __restrict__ bincnt,
                                                float* __restrict__ partial)
{
    __shared__ float bins_s[NG];
    const int t = threadIdx.x;
    const int bid = blockIdx.x;                 // grid = BINS * (BCAP/32)
    const int bin = bid / (BCAP / 32);
    const int r0  = (bid % (BCAP / 32)) * 32;
    const int cnt = min(bincnt[bin], BCAP);
    if (r0 >= cnt) return;                      // uniform: whole block empty

    bins_s[t] = 0.f;
    __syncthreads();

    const int ri = r0 + (t >> 3);
    const int v = t & 7;                        // v = 0..6 active, lane 7 dummy
    if (ri < cnt) {
        const float* rec = binbuf + ((size_t)bin * BCAP + ri) * RECF;
        const int pk = ((const int*)rec)[7];
        const int bg = ((unsigned)pk) >> 21;
        const int s  = ((const int*)rec)[8];
        const float px = rec[9], py = rec[10], pz = rec[11];
        const float r2 = px*px + py*py + pz*pz;
        const float h0 = 1.7320508f*px, h1 = 1.7320508f*py, h2 = 1.7320508f*pz;
        const float h3 = 3.8729833f*px*py, h4 = 3.8729833f*py*pz;
        const float h5 = 1.1180340f*(3.f*pz*pz - r2);
        const float h6 = 3.8729833f*px*pz;
        const float h7 = 1.9364917f*(px*px - py*py);

        const float* r = rtab + (size_t)s * 64;
        const float eav = (v < 7) ? rec[v] : 0.f;

        float tsum = r[v];                      // shfac[0] = 1
        tsum += h0 * r[ 7 + v];
        tsum += h1 * r[14 + v];
        tsum += h2 * r[21 + v];
        tsum += h3 * r[28 + v];
        tsum += h4 * r[35 + v];
        tsum += h5 * r[42 + v];
        tsum += h6 * r[49 + v];
        tsum += h7 * r[56 + v];

        float g = eav * tsum;
        g += __shfl_xor(g, 1);                  // reduce 8-lane group
        g += __shfl_xor(g, 2);
        g += __shfl_xor(g, 4);
        if (v == 0) atomicAdd(&bins_s[bg], g);  // LDS atomic, 1 per record
    }

    __syncthreads();
    unsafeAtomicAdd(&partial[(bid & (PROWS - 1)) * NG + t], bins_s[t]);
}

// ---------------- K6: reduce PROWS partial rows -> out ----------------

__global__ __launch_bounds__(256) void k_reduce(const float* __restrict__ partial,
                                                float* __restrict__ out)
{
    const int t = threadIdx.x;
    float s = 0.f;
#pragma unroll
    for (int i = 0; i < PROWS; ++i) s += partial[i * NG + t];
    out[t] = s;
}

extern "C" void kernel_launch(void* const* d_in, const int* in_sizes, int n_in,
                              void* d_out, int out_size, void* d_ws, size_t ws_size,
                              hipStream_t stream)
{
    const float* pos  = (const float*)d_in[0];
    const float* x    = (const float*)d_in[1];
    const float* eag  = (const float*)d_in[2];
    const int*   eidx = (const int*)d_in[3];
    const int*   batch= (const int*)d_in[4];
    const float* W1   = (const float*)d_in[5];
    const float* W2   = (const float*)d_in[6];
    const float* W3   = (const float*)d_in[7];
    const float* V1   = (const float*)d_in[8];
    const float* V2   = (const float*)d_in[9];
    const float* V3   = (const float*)d_in[10];
    const int* esrc = eidx;
    const int* edst = eidx + NE;

    char* ws = (char*)d_ws;
    size_t off = 0;
    auto alloc = [&](size_t bytes) -> void* {
        void* p = ws + off;
        off = (off + bytes + 255) & ~(size_t)255;
        return p;
    };
    float* yq     = (float*)alloc((size_t)NN * CAPD * YQS * sizeof(float)); // 122.9 MB
    float* binbuf = (float*)alloc((size_t)BINS * BCAP * RECF * sizeof(float)); // 17.7 MB
    float* Ztab   = (float*)alloc((size_t)NN * ZS * sizeof(float));         // 11.8 MB
    float* rtab   = (float*)alloc((size_t)NN * 64 * sizeof(float));         // 5.1 MB
    float* WV     = (float*)alloc((size_t)23 * 147 * sizeof(float));        // 13.5 KB
    int*   deg_d  = (int*)alloc((size_t)NN * sizeof(int));     // ---- zeroed region
    int*   bincnt = (int*)alloc((size_t)BINS * sizeof(int));
    float* partial= (float*)alloc((size_t)PROWS * NG * sizeof(float));
    char*  zend   = (char*)ws + off;

    hipMemsetAsync(deg_d, 0, (size_t)(zend - (char*)deg_d), stream);

    k_wv<<<14, 256, 0, stream>>>(W1, W2, W3, V1, V2, V3, WV);
    k_binsort<<<NE/256, 256, 0, stream>>>(pos, eag, esrc, edst, batch,
                                          deg_d, bincnt, binbuf);
    k_ztab<<<NN/8, 256, 0, stream>>>(x, WV, Ztab);
    k_yedge<<<BINS * (BCAP/8), 256, 0, stream>>>(Ztab, binbuf, bincnt, yq);
    k_racc<<<NN/4, 256, 0, stream>>>(yq, deg_d, rtab);
    k_gfinal<<<BINS * (BCAP/32), 256, 0, stream>>>(rtab, binbuf, bincnt, partial);
    k_reduce<<<1, 256, 0, stream>>>(partial, (float*)d_out);
}